// Round 16
// baseline (160.564 us; speedup 1.0000x reference)
//
#include <hip/hip_runtime.h>
#include <hip/hip_fp16.h>

// 3-layer GCN, pull-mode CSR gather, aggregate-before-transform, fp16 feature
// storage, packed-fp16 4-edge partial sums. R16: 16-node tiles (L3: TPB=128,
// L2: TPB=64 single-wave) -> 6250 blocks/layer, smoothing the degree-imbalance
// tail R15 exposed (35% occupancy, wave iterates max-deg of its node-groups).
// CSR: fixed-capacity buckets (no hist/scan), ms_scatter IPT=8.
// R14 lesson stands: no LDS-atomic edge-parallel gather.

#define TPB 256
#define BSH 8                 // 256 nodes per bucket
#define NBMAX 512             // bucket slots (nb = 391 actual)
#define IPT 8                 // edges per thread in ms_scatter
#define CAP 5120              // per-bucket capacity (mean 4096, +16 sigma)

static inline int cdiv(long long a, int b) { return (int)((a + b - 1) / b); }

typedef __attribute__((ext_vector_type(2))) float v2f;

struct alignas(16) h8 { __half2 a, b, c, d; };  // 8 halves = 16 B
struct alignas(8)  h4 { __half2 a, b; };        // 4 halves = 8 B

static __device__ __forceinline__ h8 add8(const h8& x, const h8& y) {
    h8 r;
    r.a = __hadd2(x.a, y.a); r.b = __hadd2(x.b, y.b);
    r.c = __hadd2(x.c, y.c); r.d = __hadd2(x.d, y.d);
    return r;
}
static __device__ __forceinline__ void flushA(v2f* A, const h8& s) {
    float2 f;
    f = __half22float2(s.a); { v2f t; t.x = f.x; t.y = f.y; A[0] += t; }
    f = __half22float2(s.b); { v2f t; t.x = f.x; t.y = f.y; A[1] += t; }
    f = __half22float2(s.c); { v2f t; t.x = f.x; t.y = f.y; A[2] += t; }
    f = __half22float2(s.d); { v2f t; t.x = f.x; t.y = f.y; A[3] += t; }
}

// bcur[b] = b*CAP (append cursors, fixed-capacity regions)
__global__ __launch_bounds__(TPB) void init_bcur(int* __restrict__ bcur, int m) {
    int i = blockIdx.x * TPB + threadIdx.x;
    if (i < m) bcur[i] = i * CAP;
}

// pairs packed: src (24 bits) | local-dst (8 bits, dst & 255) << 24
__global__ __launch_bounds__(TPB) void ms_scatter(const int* __restrict__ src,
                                                  const int* __restrict__ dst,
                                                  int* __restrict__ bcur,
                                                  int* __restrict__ pairs, int e) {
    __shared__ int h[NBMAX];
    __shared__ int sbase[NBMAX];
    int tid = threadIdx.x;
    h[tid] = 0; h[tid + TPB] = 0;
    __syncthreads();
    int base = blockIdx.x * (TPB * IPT);
#pragma unroll 8
    for (int k = 0; k < IPT; ++k) {
        int i = base + k * TPB + tid;
        if (i < e) atomicAdd(&h[dst[i] >> BSH], 1);
    }
    __syncthreads();
    int v0 = h[tid], v1 = h[tid + TPB];
    if (v0) sbase[tid] = atomicAdd(&bcur[tid], v0);
    if (v1) sbase[tid + TPB] = atomicAdd(&bcur[tid + TPB], v1);
    __syncthreads();
#pragma unroll 8
    for (int k = 0; k < IPT; ++k) {
        int i = base + k * TPB + tid;
        if (i < e) {
            int s = src[i], d = dst[i];
            int b = d >> BSH;
            int pos = atomicAdd(&sbase[b], 1);
            if (pos < (b + 1) * CAP)  // capacity guard (memory safety)
                pairs[pos] = s | ((d & 255) << 24);
        }
    }
}

// one WG per bucket: histogram -> scan -> rowptr/rowend/dinv -> csr placement
__global__ __launch_bounds__(TPB) void build_csr(const int* __restrict__ pairs,
                                                 const int* __restrict__ bcur,
                                                 int* __restrict__ rowptr,
                                                 int* __restrict__ rowend,
                                                 float* __restrict__ dinv,
                                                 int* __restrict__ csr, int n) {
    int b = blockIdx.x;
    int p0 = b * CAP;
    int p1 = bcur[b];
    if (p1 > p0 + CAP) p1 = p0 + CAP;
    __shared__ int scnt[TPB];
    __shared__ int sbase[TPB];
    __shared__ int lds[TPB];
    int tid = threadIdx.x;
    scnt[tid] = 0;
    __syncthreads();
    for (int j = p0 + tid; j < p1; j += TPB)
        atomicAdd(&scnt[((unsigned)pairs[j]) >> 24], 1);
    __syncthreads();
    int c = scnt[tid];
    lds[tid] = c;
    __syncthreads();
    for (int off = 1; off < TPB; off <<= 1) {
        int x = (tid >= off) ? lds[tid - off] : 0;
        __syncthreads();
        lds[tid] += x;
        __syncthreads();
    }
    int excl = lds[tid] - c;
    sbase[tid] = p0 + excl;
    int node = (b << BSH) + tid;
    if (node < n) {
        rowptr[node] = p0 + excl;
        rowend[node] = p0 + excl + c;
        dinv[node] = rsqrtf(1.0f + (float)c);  // +1 self-loop
    }
    __syncthreads();
    for (int j = p0 + tid; j < p1; j += TPB) {
        int pr = pairs[j];
        int pos = atomicAdd(&sbase[((unsigned)pr) >> 24], 1);
        csr[pos] = pr & 0xFFFFFF;
    }
}

// xs[i][k] = half( x[i][k] * dinv[i] )
template <int K>
__global__ __launch_bounds__(TPB) void prescale(const float* __restrict__ x,
                                                const float* __restrict__ dinv,
                                                __half* __restrict__ xs, int n) {
    int idx = blockIdx.x * TPB + threadIdx.x;
    if (idx < n * K) xs[idx] = __float2half(x[idx] * dinv[idx / K]);
}

static __device__ __forceinline__ void acc4f(float* a, const h4& v) {
    float2 f;
    f = __half22float2(v.a); a[0] += f.x; a[1] += f.y;
    f = __half22float2(v.b); a[2] += f.x; a[3] += f.y;
}

// ---- fused layer: agg (fp16 gather -> f32 LDS tile) + dense transform ----
template <int TPBT, int K, int CO, int NODES, bool RELU_OUT, bool SCALE_OUT, bool OUT_HALF>
__global__ __launch_bounds__(TPBT) void fused_layer(const __half* __restrict__ hs,
                                                    const int* __restrict__ rowptr,
                                                    const int* __restrict__ rowend,
                                                    const int* __restrict__ csr,
                                                    const float* __restrict__ dinv,
                                                    const float* __restrict__ W,
                                                    const float* __restrict__ bias,
                                                    void* __restrict__ outv, int n) {
    __shared__ float tile[NODES * K];
    int i0 = blockIdx.x * NODES;

    // ================= phase A: gather =================
    if constexpr (K == 4) {
        static_assert(NODES == TPBT, "K=4 path: one node per thread");
        const h4* hv = (const h4*)hs;
        int ln = threadIdx.x;
        int i = i0 + ln;
        if (i < n) {
            float a[4] = {0.f, 0.f, 0.f, 0.f};
            acc4f(a, hv[i]);  // self-loop
            int j = rowptr[i], re = rowend[i];
            for (; j + 8 <= re; j += 8) {
                h4 v0 = hv[csr[j + 0]], v1 = hv[csr[j + 1]], v2 = hv[csr[j + 2]], v3 = hv[csr[j + 3]];
                h4 v4 = hv[csr[j + 4]], v5 = hv[csr[j + 5]], v6 = hv[csr[j + 6]], v7 = hv[csr[j + 7]];
                acc4f(a, v0); acc4f(a, v1); acc4f(a, v2); acc4f(a, v3);
                acc4f(a, v4); acc4f(a, v5); acc4f(a, v6); acc4f(a, v7);
            }
            for (; j < re; ++j) acc4f(a, hv[csr[j]]);
            float di = dinv[i];
            *(float4*)(tile + ln * 4) =
                make_float4(a[0] * di, a[1] * di, a[2] * di, a[3] * di);
        }
    } else {
        constexpr int L = K / 8;             // 16B lanes per node
        constexpr int NGRP = TPBT / L;       // nodes per round
        static_assert(NGRP == NODES, "all threads active in phase A");
        const h8* hv = (const h8*)hs;
        int cl = threadIdx.x % L, grp = threadIdx.x / L;
        int i = i0 + grp;
        if (i < n) {
            v2f A[4];
            A[0] = 0.f; A[1] = 0.f; A[2] = 0.f; A[3] = 0.f;
            flushA(A, hv[(size_t)i * L + cl]);  // self-loop
            int j = rowptr[i], re = rowend[i];
            for (; j + 8 <= re; j += 8) {
                h8 v0 = hv[(size_t)csr[j + 0] * L + cl], v1 = hv[(size_t)csr[j + 1] * L + cl];
                h8 v2 = hv[(size_t)csr[j + 2] * L + cl], v3 = hv[(size_t)csr[j + 3] * L + cl];
                h8 v4 = hv[(size_t)csr[j + 4] * L + cl], v5 = hv[(size_t)csr[j + 5] * L + cl];
                h8 v6 = hv[(size_t)csr[j + 6] * L + cl], v7 = hv[(size_t)csr[j + 7] * L + cl];
                flushA(A, add8(add8(v0, v1), add8(v2, v3)));  // 4-edge fp16 partial
                flushA(A, add8(add8(v4, v5), add8(v6, v7)));
            }
            if (j + 4 <= re) {
                h8 v0 = hv[(size_t)csr[j + 0] * L + cl], v1 = hv[(size_t)csr[j + 1] * L + cl];
                h8 v2 = hv[(size_t)csr[j + 2] * L + cl], v3 = hv[(size_t)csr[j + 3] * L + cl];
                flushA(A, add8(add8(v0, v1), add8(v2, v3)));
                j += 4;
            }
            for (; j < re; ++j) flushA(A, hv[(size_t)csr[j] * L + cl]);
            float di = dinv[i];
            float4* t4 = (float4*)(tile + grp * K + cl * 8);
            t4[0] = make_float4(A[0].x * di, A[0].y * di, A[1].x * di, A[1].y * di);
            t4[1] = make_float4(A[2].x * di, A[2].y * di, A[3].x * di, A[3].y * di);
        }
    }
    __syncthreads();

    // ================= phase B: dense transform =================
    constexpr int SLOTS = TPBT / CO;
    constexpr int HB = (NODES < SLOTS * 8) ? NODES : SLOTS * 8;  // node sub-block
    constexpr int NPT = HB / SLOTS;                              // <= 8
    constexpr int KT = (K > 16) ? 16 : K;
    int c = threadIdx.x % CO;
    int slot = threadIdx.x / CO;
    float bc = bias[c];

#pragma unroll 1
    for (int hb = 0; hb < NODES; hb += HB) {
        float acc[NPT];
#pragma unroll
        for (int t = 0; t < NPT; ++t) acc[t] = 0.0f;

#pragma unroll 1
        for (int p = 0; p < K; p += KT) {
            float wc[KT];
#pragma unroll
            for (int k = 0; k < KT; ++k) wc[k] = W[(size_t)(p + k) * CO + c];
#pragma unroll
            for (int t = 0; t < NPT; ++t) {
                const float4* row = (const float4*)(tile + (hb + slot * NPT + t) * K + p);
#pragma unroll
                for (int q = 0; q < KT / 4; ++q) {
                    float4 r = row[q];
                    acc[t] = fmaf(r.x, wc[4 * q + 0], acc[t]);
                    acc[t] = fmaf(r.y, wc[4 * q + 1], acc[t]);
                    acc[t] = fmaf(r.z, wc[4 * q + 2], acc[t]);
                    acc[t] = fmaf(r.w, wc[4 * q + 3], acc[t]);
                }
            }
        }
#pragma unroll
        for (int t = 0; t < NPT; ++t) {
            int i = i0 + hb + slot * NPT + t;
            if (i < n) {
                float v = acc[t] + bc;
                if (RELU_OUT) v = fmaxf(v, 0.0f);
                if (SCALE_OUT) v *= dinv[i];
                if (OUT_HALF)
                    ((__half*)outv)[(size_t)i * CO + c] = __float2half(v);
                else
                    ((float*)outv)[(size_t)i * CO + c] = v;
            }
        }
    }
}

extern "C" void kernel_launch(void* const* d_in, const int* in_sizes, int n_in,
                              void* d_out, int out_size, void* d_ws, size_t ws_size,
                              hipStream_t stream) {
    const float* x  = (const float*)d_in[0];
    const int*   ei = (const int*)d_in[1];
    const float* W1 = (const float*)d_in[2];
    const float* b1 = (const float*)d_in[3];
    const float* W2 = (const float*)d_in[4];
    const float* b2 = (const float*)d_in[5];
    const float* W3 = (const float*)d_in[6];
    const float* b3 = (const float*)d_in[7];
    float* out = (float*)d_out;

    const int n = in_sizes[0] / 4;   // 100000
    const int e = in_sizes[1] / 2;   // 1600000
    const int* src = ei;
    const int* dst = ei + e;
    const int nb = cdiv(n, 1 << BSH);  // 391 buckets

    char* ws = (char*)d_ws;
    size_t off = 0;
    auto carve = [&](size_t bytes) {
        char* p = ws + off;
        off = (off + bytes + 255) & ~(size_t)255;
        return p;
    };
    float*  dinv   = (float*) carve((size_t)n * 4);
    int*    rowptr = (int*)   carve((size_t)n * 4);
    int*    rowend = (int*)   carve((size_t)n * 4);
    int*    bcur   = (int*)   carve((size_t)(NBMAX + 1) * 4);
    int*    csr    = (int*)   carve((size_t)NBMAX * CAP * 4);  // 10.5 MB (gapped)
    int*    pairs  = (int*)   carve((size_t)NBMAX * CAP * 4);  // 10.5 MB (gapped)
    __half* Ah     = (__half*)carve((size_t)n * 64 * 2);       // h2s fp16
    __half* Bh     = (__half*)carve((size_t)n * 32 * 2);       // h1s fp16
    __half* xs     = (__half*)carve((size_t)n * 4 * 2);        // prescaled x fp16

    const int eblk = cdiv(e, TPB * IPT);  // 782 blocks over edges

    // ---- CSR + norms (fixed-capacity bucket scatter, no hist/scan pass) ----
    init_bcur<<<cdiv(NBMAX + 1, TPB), TPB, 0, stream>>>(bcur, NBMAX + 1);
    ms_scatter<<<eblk, TPB, 0, stream>>>(src, dst, bcur, pairs, e);
    build_csr<<<nb, TPB, 0, stream>>>(pairs, bcur, rowptr, rowend, dinv, csr, n);

    // ---- layer 1: xs = half(x*dinv); fused agg(K=4)+xw(4->32) -> Bh ----
    prescale<4><<<cdiv((long long)n * 4, TPB), TPB, 0, stream>>>(x, dinv, xs, n);
    fused_layer<256, 4, 32, 256, true, true, true><<<cdiv(n, 256), 256, 0, stream>>>(
        xs, rowptr, rowend, csr, dinv, W1, b1, Bh, n);

    // ---- layer 2: fused agg(K=32)+xw(32->64) -> Ah  (TPB=64, 16-node tiles) ----
    fused_layer<64, 32, 64, 16, true, true, true><<<cdiv(n, 16), 64, 0, stream>>>(
        Bh, rowptr, rowend, csr, dinv, W2, b2, Ah, n);

    // ---- layer 3: fused agg(K=64)+xw(64->64) -> out (TPB=128, 16-node tiles) ----
    fused_layer<128, 64, 64, 16, false, false, false><<<cdiv(n, 16), 128, 0, stream>>>(
        Ah, rowptr, rowend, csr, dinv, W3, b3, out, n);
}

// Round 17
// 154.395 us; speedup vs baseline: 1.0400x; 1.0400x over previous
//
#include <hip/hip_runtime.h>
#include <hip/hip_fp16.h>

// 3-layer GCN, pull-mode CSR gather, aggregate-before-transform, fp16 feature
// storage, packed-fp16 4-edge partial sums. R17 = R15 config restored (R16's
// 16-node tiles regressed) + software-pipelined csr index loads in the gather
// (preload next batch's 8 indices before consuming current batch's features).
// Diagnosis (R16): layer time == compulsory L2-fill (hs_bytes x 8 XCDs) at the
// ~1.7 TB/s random-demand L3->L2 rate -> near structural floor.
// Lessons kept: no LDS-atomic edge-parallel gather (R14), bounded live set
// (R8), node-parallel gather with fp16 4-edge partial trees (R12).

#define TPB 256
#define BSH 8                 // 256 nodes per bucket
#define NBMAX 512             // bucket slots (nb = 391 actual)
#define IPT 16                // edges per thread in ms_scatter
#define CAP 5120              // per-bucket capacity (mean 4096, +16 sigma)

static inline int cdiv(long long a, int b) { return (int)((a + b - 1) / b); }

typedef __attribute__((ext_vector_type(2))) float v2f;

struct alignas(16) h8 { __half2 a, b, c, d; };  // 8 halves = 16 B
struct alignas(8)  h4 { __half2 a, b; };        // 4 halves = 8 B

static __device__ __forceinline__ h8 add8(const h8& x, const h8& y) {
    h8 r;
    r.a = __hadd2(x.a, y.a); r.b = __hadd2(x.b, y.b);
    r.c = __hadd2(x.c, y.c); r.d = __hadd2(x.d, y.d);
    return r;
}
static __device__ __forceinline__ void flushA(v2f* A, const h8& s) {
    float2 f;
    f = __half22float2(s.a); { v2f t; t.x = f.x; t.y = f.y; A[0] += t; }
    f = __half22float2(s.b); { v2f t; t.x = f.x; t.y = f.y; A[1] += t; }
    f = __half22float2(s.c); { v2f t; t.x = f.x; t.y = f.y; A[2] += t; }
    f = __half22float2(s.d); { v2f t; t.x = f.x; t.y = f.y; A[3] += t; }
}

// bcur[b] = b*CAP (append cursors, fixed-capacity regions)
__global__ __launch_bounds__(TPB) void init_bcur(int* __restrict__ bcur, int m) {
    int i = blockIdx.x * TPB + threadIdx.x;
    if (i < m) bcur[i] = i * CAP;
}

// pairs packed: src (24 bits) | local-dst (8 bits, dst & 255) << 24
__global__ __launch_bounds__(TPB) void ms_scatter(const int* __restrict__ src,
                                                  const int* __restrict__ dst,
                                                  int* __restrict__ bcur,
                                                  int* __restrict__ pairs, int e) {
    __shared__ int h[NBMAX];
    __shared__ int sbase[NBMAX];
    int tid = threadIdx.x;
    h[tid] = 0; h[tid + TPB] = 0;
    __syncthreads();
    int base = blockIdx.x * (TPB * IPT);
#pragma unroll 8
    for (int k = 0; k < IPT; ++k) {
        int i = base + k * TPB + tid;
        if (i < e) atomicAdd(&h[dst[i] >> BSH], 1);
    }
    __syncthreads();
    int v0 = h[tid], v1 = h[tid + TPB];
    if (v0) sbase[tid] = atomicAdd(&bcur[tid], v0);
    if (v1) sbase[tid + TPB] = atomicAdd(&bcur[tid + TPB], v1);
    __syncthreads();
#pragma unroll 8
    for (int k = 0; k < IPT; ++k) {
        int i = base + k * TPB + tid;
        if (i < e) {
            int s = src[i], d = dst[i];
            int b = d >> BSH;
            int pos = atomicAdd(&sbase[b], 1);
            if (pos < (b + 1) * CAP)  // capacity guard (memory safety)
                pairs[pos] = s | ((d & 255) << 24);
        }
    }
}

// one WG per bucket: histogram -> scan -> rowptr/rowend/dinv -> csr placement
__global__ __launch_bounds__(TPB) void build_csr(const int* __restrict__ pairs,
                                                 const int* __restrict__ bcur,
                                                 int* __restrict__ rowptr,
                                                 int* __restrict__ rowend,
                                                 float* __restrict__ dinv,
                                                 int* __restrict__ csr, int n) {
    int b = blockIdx.x;
    int p0 = b * CAP;
    int p1 = bcur[b];
    if (p1 > p0 + CAP) p1 = p0 + CAP;
    __shared__ int scnt[TPB];
    __shared__ int sbase[TPB];
    __shared__ int lds[TPB];
    int tid = threadIdx.x;
    scnt[tid] = 0;
    __syncthreads();
    for (int j = p0 + tid; j < p1; j += TPB)
        atomicAdd(&scnt[((unsigned)pairs[j]) >> 24], 1);
    __syncthreads();
    int c = scnt[tid];
    lds[tid] = c;
    __syncthreads();
    for (int off = 1; off < TPB; off <<= 1) {
        int x = (tid >= off) ? lds[tid - off] : 0;
        __syncthreads();
        lds[tid] += x;
        __syncthreads();
    }
    int excl = lds[tid] - c;
    sbase[tid] = p0 + excl;
    int node = (b << BSH) + tid;
    if (node < n) {
        rowptr[node] = p0 + excl;
        rowend[node] = p0 + excl + c;
        dinv[node] = rsqrtf(1.0f + (float)c);  // +1 self-loop
    }
    __syncthreads();
    for (int j = p0 + tid; j < p1; j += TPB) {
        int pr = pairs[j];
        int pos = atomicAdd(&sbase[((unsigned)pr) >> 24], 1);
        csr[pos] = pr & 0xFFFFFF;
    }
}

// xs[i][k] = half( x[i][k] * dinv[i] )
template <int K>
__global__ __launch_bounds__(TPB) void prescale(const float* __restrict__ x,
                                                const float* __restrict__ dinv,
                                                __half* __restrict__ xs, int n) {
    int idx = blockIdx.x * TPB + threadIdx.x;
    if (idx < n * K) xs[idx] = __float2half(x[idx] * dinv[idx / K]);
}

static __device__ __forceinline__ void acc4f(float* a, const h4& v) {
    float2 f;
    f = __half22float2(v.a); a[0] += f.x; a[1] += f.y;
    f = __half22float2(v.b); a[2] += f.x; a[3] += f.y;
}

// ---- fused layer: agg (fp16 gather -> f32 LDS tile) + dense transform ----
template <int TPBT, int K, int CO, int NODES, bool RELU_OUT, bool SCALE_OUT, bool OUT_HALF>
__global__ __launch_bounds__(TPBT) void fused_layer(const __half* __restrict__ hs,
                                                    const int* __restrict__ rowptr,
                                                    const int* __restrict__ rowend,
                                                    const int* __restrict__ csr,
                                                    const float* __restrict__ dinv,
                                                    const float* __restrict__ W,
                                                    const float* __restrict__ bias,
                                                    void* __restrict__ outv, int n) {
    __shared__ float tile[NODES * K];
    int i0 = blockIdx.x * NODES;

    // ================= phase A: gather =================
    if constexpr (K == 4) {
        static_assert(NODES == TPBT, "K=4 path: one node per thread");
        const h4* hv = (const h4*)hs;
        int ln = threadIdx.x;
        int i = i0 + ln;
        if (i < n) {
            float a[4] = {0.f, 0.f, 0.f, 0.f};
            acc4f(a, hv[i]);  // self-loop
            int j = rowptr[i], re = rowend[i];
            for (; j + 8 <= re; j += 8) {
                h4 v0 = hv[csr[j + 0]], v1 = hv[csr[j + 1]], v2 = hv[csr[j + 2]], v3 = hv[csr[j + 3]];
                h4 v4 = hv[csr[j + 4]], v5 = hv[csr[j + 5]], v6 = hv[csr[j + 6]], v7 = hv[csr[j + 7]];
                acc4f(a, v0); acc4f(a, v1); acc4f(a, v2); acc4f(a, v3);
                acc4f(a, v4); acc4f(a, v5); acc4f(a, v6); acc4f(a, v7);
            }
            for (; j < re; ++j) acc4f(a, hv[csr[j]]);
            float di = dinv[i];
            *(float4*)(tile + ln * 4) =
                make_float4(a[0] * di, a[1] * di, a[2] * di, a[3] * di);
        }
    } else {
        constexpr int L = K / 8;             // 16B lanes per node
        constexpr int NGRP = TPBT / L;       // nodes per round
        static_assert(NGRP == NODES, "all threads active in phase A");
        const h8* hv = (const h8*)hs;
        int cl = threadIdx.x % L, grp = threadIdx.x / L;
        int i = i0 + grp;
        if (i < n) {
            v2f A[4];
            A[0] = 0.f; A[1] = 0.f; A[2] = 0.f; A[3] = 0.f;
            flushA(A, hv[(size_t)i * L + cl]);  // self-loop
            int j = rowptr[i], re = rowend[i];
            // software-pipelined 8-edge batches: preload next batch's indices
            int c0, c1, c2, c3, c4, c5, c6, c7;
            bool have = (j + 8 <= re);
            if (have) {
                c0 = csr[j + 0]; c1 = csr[j + 1]; c2 = csr[j + 2]; c3 = csr[j + 3];
                c4 = csr[j + 4]; c5 = csr[j + 5]; c6 = csr[j + 6]; c7 = csr[j + 7];
            }
            while (have) {
                int jn = j + 8;
                bool haveNext = (jn + 8 <= re);
                int d0, d1, d2, d3, d4, d5, d6, d7;
                if (haveNext) {
                    d0 = csr[jn + 0]; d1 = csr[jn + 1]; d2 = csr[jn + 2]; d3 = csr[jn + 3];
                    d4 = csr[jn + 4]; d5 = csr[jn + 5]; d6 = csr[jn + 6]; d7 = csr[jn + 7];
                }
                h8 v0 = hv[(size_t)c0 * L + cl], v1 = hv[(size_t)c1 * L + cl];
                h8 v2 = hv[(size_t)c2 * L + cl], v3 = hv[(size_t)c3 * L + cl];
                h8 v4 = hv[(size_t)c4 * L + cl], v5 = hv[(size_t)c5 * L + cl];
                h8 v6 = hv[(size_t)c6 * L + cl], v7 = hv[(size_t)c7 * L + cl];
                flushA(A, add8(add8(v0, v1), add8(v2, v3)));  // 4-edge fp16 partial
                flushA(A, add8(add8(v4, v5), add8(v6, v7)));
                j = jn;
                have = haveNext;
                c0 = d0; c1 = d1; c2 = d2; c3 = d3;
                c4 = d4; c5 = d5; c6 = d6; c7 = d7;
            }
            if (j + 4 <= re) {
                h8 v0 = hv[(size_t)csr[j + 0] * L + cl], v1 = hv[(size_t)csr[j + 1] * L + cl];
                h8 v2 = hv[(size_t)csr[j + 2] * L + cl], v3 = hv[(size_t)csr[j + 3] * L + cl];
                flushA(A, add8(add8(v0, v1), add8(v2, v3)));
                j += 4;
            }
            for (; j < re; ++j) flushA(A, hv[(size_t)csr[j] * L + cl]);
            float di = dinv[i];
            float4* t4 = (float4*)(tile + grp * K + cl * 8);
            t4[0] = make_float4(A[0].x * di, A[0].y * di, A[1].x * di, A[1].y * di);
            t4[1] = make_float4(A[2].x * di, A[2].y * di, A[3].x * di, A[3].y * di);
        }
    }
    __syncthreads();

    // ================= phase B: dense transform =================
    constexpr int SLOTS = TPBT / CO;
    constexpr int HB = (NODES < SLOTS * 8) ? NODES : SLOTS * 8;  // node sub-block
    constexpr int NPT = HB / SLOTS;                              // <= 8
    constexpr int KT = (K > 16) ? 16 : K;
    int c = threadIdx.x % CO;
    int slot = threadIdx.x / CO;
    float bc = bias[c];

#pragma unroll 1
    for (int hb = 0; hb < NODES; hb += HB) {
        float acc[NPT];
#pragma unroll
        for (int t = 0; t < NPT; ++t) acc[t] = 0.0f;

#pragma unroll 1
        for (int p = 0; p < K; p += KT) {
            float wc[KT];
#pragma unroll
            for (int k = 0; k < KT; ++k) wc[k] = W[(size_t)(p + k) * CO + c];
#pragma unroll
            for (int t = 0; t < NPT; ++t) {
                const float4* row = (const float4*)(tile + (hb + slot * NPT + t) * K + p);
#pragma unroll
                for (int q = 0; q < KT / 4; ++q) {
                    float4 r = row[q];
                    acc[t] = fmaf(r.x, wc[4 * q + 0], acc[t]);
                    acc[t] = fmaf(r.y, wc[4 * q + 1], acc[t]);
                    acc[t] = fmaf(r.z, wc[4 * q + 2], acc[t]);
                    acc[t] = fmaf(r.w, wc[4 * q + 3], acc[t]);
                }
            }
        }
#pragma unroll
        for (int t = 0; t < NPT; ++t) {
            int i = i0 + hb + slot * NPT + t;
            if (i < n) {
                float v = acc[t] + bc;
                if (RELU_OUT) v = fmaxf(v, 0.0f);
                if (SCALE_OUT) v *= dinv[i];
                if (OUT_HALF)
                    ((__half*)outv)[(size_t)i * CO + c] = __float2half(v);
                else
                    ((float*)outv)[(size_t)i * CO + c] = v;
            }
        }
    }
}

extern "C" void kernel_launch(void* const* d_in, const int* in_sizes, int n_in,
                              void* d_out, int out_size, void* d_ws, size_t ws_size,
                              hipStream_t stream) {
    const float* x  = (const float*)d_in[0];
    const int*   ei = (const int*)d_in[1];
    const float* W1 = (const float*)d_in[2];
    const float* b1 = (const float*)d_in[3];
    const float* W2 = (const float*)d_in[4];
    const float* b2 = (const float*)d_in[5];
    const float* W3 = (const float*)d_in[6];
    const float* b3 = (const float*)d_in[7];
    float* out = (float*)d_out;

    const int n = in_sizes[0] / 4;   // 100000
    const int e = in_sizes[1] / 2;   // 1600000
    const int* src = ei;
    const int* dst = ei + e;
    const int nb = cdiv(n, 1 << BSH);  // 391 buckets

    char* ws = (char*)d_ws;
    size_t off = 0;
    auto carve = [&](size_t bytes) {
        char* p = ws + off;
        off = (off + bytes + 255) & ~(size_t)255;
        return p;
    };
    float*  dinv   = (float*) carve((size_t)n * 4);
    int*    rowptr = (int*)   carve((size_t)n * 4);
    int*    rowend = (int*)   carve((size_t)n * 4);
    int*    bcur   = (int*)   carve((size_t)(NBMAX + 1) * 4);
    int*    csr    = (int*)   carve((size_t)NBMAX * CAP * 4);  // 10.5 MB (gapped)
    int*    pairs  = (int*)   carve((size_t)NBMAX * CAP * 4);  // 10.5 MB (gapped)
    __half* Ah     = (__half*)carve((size_t)n * 64 * 2);       // h2s fp16
    __half* Bh     = (__half*)carve((size_t)n * 32 * 2);       // h1s fp16
    __half* xs     = (__half*)carve((size_t)n * 4 * 2);        // prescaled x fp16

    const int eblk = cdiv(e, TPB * IPT);  // 391 blocks over edges

    // ---- CSR + norms (fixed-capacity bucket scatter, no hist/scan pass) ----
    init_bcur<<<cdiv(NBMAX + 1, TPB), TPB, 0, stream>>>(bcur, NBMAX + 1);
    ms_scatter<<<eblk, TPB, 0, stream>>>(src, dst, bcur, pairs, e);
    build_csr<<<nb, TPB, 0, stream>>>(pairs, bcur, rowptr, rowend, dinv, csr, n);

    // ---- layer 1: xs = half(x*dinv); fused agg(K=4)+xw(4->32) -> Bh ----
    prescale<4><<<cdiv((long long)n * 4, TPB), TPB, 0, stream>>>(x, dinv, xs, n);
    fused_layer<256, 4, 32, 256, true, true, true><<<cdiv(n, 256), 256, 0, stream>>>(
        xs, rowptr, rowend, csr, dinv, W1, b1, Bh, n);

    // ---- layer 2: fused agg(K=32)+xw(32->64) -> Ah  (TPB=128, 32-node tiles) ----
    fused_layer<128, 32, 64, 32, true, true, true><<<cdiv(n, 32), 128, 0, stream>>>(
        Bh, rowptr, rowend, csr, dinv, W2, b2, Ah, n);

    // ---- layer 3: fused agg(K=64)+xw(64->64) -> out (f32, 32-node tiles) ----
    fused_layer<256, 64, 64, 32, false, false, false><<<cdiv(n, 32), 256, 0, stream>>>(
        Ah, rowptr, rowend, csr, dinv, W3, b3, out, n);
}